// Round 3
// baseline (568.007 us; speedup 1.0000x reference)
//
#include <hip/hip_runtime.h>
#include <stdint.h>

#define BS 128
#define SL 512
#define HD 1024
#define DD 512
#define M_TOT (BS*SL)   // 65536

typedef __attribute__((ext_vector_type(8))) short short8;
typedef __attribute__((ext_vector_type(4))) float f32x4;

__device__ __forceinline__ unsigned short f32_bf16(float f) {
    union { float f; unsigned u; } v; v.f = f;
    unsigned u = v.u + 0x7FFFu + ((v.u >> 16) & 1u);
    return (unsigned short)(u >> 16);
}
__device__ __forceinline__ float bf16_f32(unsigned short h) {
    union { unsigned u; float f; } v; v.u = ((unsigned)h) << 16; return v.f;
}
__device__ __forceinline__ float u2f(unsigned u) {
    union { unsigned u; float f; } v; v.u = u; return v.f;
}
// packed 2xf32 -> 2xbf16 (RNE), one VOP3: d[15:0]=bf16(a), d[31:16]=bf16(b)
__device__ __forceinline__ unsigned cvt_pk_bf16(float a, float b) {
    unsigned r;
    asm("v_cvt_pk_bf16_f32 %0, %1, %2" : "=v"(r) : "v"(a), "v"(b));
    return r;
}
__device__ __forceinline__ float fast_tanh(float x) {
    float e = __expf(2.0f * x);
    return 1.0f - 2.0f / (e + 1.0f);
}
__device__ __forceinline__ void async_lds16(const void* g, void* l) {
    __builtin_amdgcn_global_load_lds(
        (const __attribute__((address_space(1))) unsigned int*)g,
        (__attribute__((address_space(3))) unsigned int*)l, 16, 0, 0);
}

// ---------------- pack Wq into bf16 hi/lo, MFMA-frag order (+ mask detect) --
__global__ void pack_wq_kernel(const float* __restrict__ Wq,
                               unsigned short* __restrict__ P,
                               const unsigned* __restrict__ mw,
                               int* __restrict__ flag) {
    if (blockIdx.x == 0) {
        unsigned bad = 0;
        for (int i = threadIdx.x; i < 1024; i += 256) bad |= (mw[i] > 1u) ? 1u : 0u;
        if (bad) atomicExch(flag, 1);
    }
    int t = blockIdx.x * 256 + threadIdx.x;   // 0..65535
    int d  = t >> 7;           // 0..511
    int h0 = (t & 127) << 3;   // 0..1016
    const float* src = Wq + (size_t)d * HD + h0;
    union { unsigned short s[8]; uint4 v; } a, b;
#pragma unroll
    for (int j = 0; j < 8; ++j) {
        float f = src[j];
        a.s[j] = f32_bf16(f);
        b.s[j] = f32_bf16(f - bf16_f32(a.s[j]));
    }
    int nb = d >> 7, cg = (d >> 4) & 7, lr = d & 15;
    int ks = h0 >> 5, q = (h0 >> 3) & 3;
    int l = q * 16 + lr;
    size_t base = (size_t)(nb * 32 + ks) * 8192 + (size_t)(cg * 64 + l) * 8;
    *(uint4*)(P + base)        = a.v;
    *(uint4*)(P + base + 4096) = b.v;
}

// ---------------- phase 1: score = vq . tanh(x @ Wq^T + bq) ----------------
// 128x128 tile, K=1024 in 32 steps. 4 waves (2x2), each 64x64 (4x4 of 16x16).
// 3-term bf16 split. UNCHANGED from round 2 (217 us, MfmaUtil 42%, VGPR 64 =
// exactly the 128-reg/4-wave budget with 64 AGPR acc). Effective 945 TF ==
// the documented ~900 TF ceiling of the 2-barrier-per-K-step structure;
// further gains need the 8-phase counted-vmcnt schedule, not source tweaks.
__launch_bounds__(256, 4)
__global__ void score_kernel(const float* __restrict__ x,
                             const unsigned short* __restrict__ packW,
                             const float* __restrict__ bq,
                             const float* __restrict__ vq,
                             float* __restrict__ score) {
    __shared__ unsigned short A_hi[4096];   // 8 KB, frag order, XOR-swizzled
    __shared__ unsigned short A_lo[4096];   // 8 KB
    __shared__ unsigned short Bt[8192];     // 16 KB: hi[0..4095], lo[4096..]

    const int bid = blockIdx.x;
    const int xcd = bid & 7;
    const int slot = bid >> 3;              // 0..255
    const int nb = slot & 3;                // N tile of 128
    const int m0 = (xcd + ((slot >> 2) << 3)) << 7;  // row tile * 128

    const int t = threadIdx.x;
    const int l = t & 63;
    const int w = t >> 6;
    const int wm = w & 1, wn = w >> 1;      // 2x2 wave grid

    f32x4 acc[4][4];
#pragma unroll
    for (int i = 0; i < 4; ++i)
#pragma unroll
        for (int j = 0; j < 4; ++j)
            acc[i][j] = (f32x4){0.f, 0.f, 0.f, 0.f};

    const char* Ahc = (const char*)A_hi;
    const char* Alc = (const char*)A_lo;

    float4 px[2][2];
    // prefetch ks=0
#pragma unroll
    for (int r = 0; r < 2; ++r) {
        int u = r * 256 + t;
        int row = u >> 2, c8 = u & 3;
        const float4* xp = (const float4*)(x + (size_t)(m0 + row) * HD + c8 * 8);
        px[r][0] = xp[0]; px[r][1] = xp[1];
    }

    for (int ks = 0; ks < 32; ++ks) {
        __syncthreads();   // previous compute done -> LDS free
        // ---- stage B: async 16KB linear copy (frag-ordered in packW) ----
        {
            const unsigned short* src = packW + (size_t)(nb * 32 + ks) * 8192;
#pragma unroll
            for (int r = 0; r < 4; ++r)
                async_lds16(src + (size_t)(r * 256 + t) * 8, Bt + (r * 256 + t) * 8);
        }
        // ---- stage A: prefetched fp32 -> bf16 hi/lo via cvt_pk, swizzled ----
#pragma unroll
        for (int r = 0; r < 2; ++r) {
            int u = r * 256 + t;
            int row = u >> 2, c8 = u & 3;
            int rg = row >> 4, rr = row & 15;
            int off = (((rg * 64 + c8 * 16 + rr) * 16) ^ (c8 << 5));
            float4 v0 = px[r][0], v1 = px[r][1];
            unsigned h0 = cvt_pk_bf16(v0.x, v0.y);
            unsigned h1 = cvt_pk_bf16(v0.z, v0.w);
            unsigned h2 = cvt_pk_bf16(v1.x, v1.y);
            unsigned h3 = cvt_pk_bf16(v1.z, v1.w);
            unsigned l0 = cvt_pk_bf16(v0.x - u2f(h0 << 16), v0.y - u2f(h0 & 0xFFFF0000u));
            unsigned l1 = cvt_pk_bf16(v0.z - u2f(h1 << 16), v0.w - u2f(h1 & 0xFFFF0000u));
            unsigned l2 = cvt_pk_bf16(v1.x - u2f(h2 << 16), v1.y - u2f(h2 & 0xFFFF0000u));
            unsigned l3 = cvt_pk_bf16(v1.z - u2f(h3 << 16), v1.w - u2f(h3 & 0xFFFF0000u));
            uint4 hv = {h0, h1, h2, h3};
            uint4 lv = {l0, l1, l2, l3};
            *(uint4*)((char*)A_hi + off) = hv;
            *(uint4*)((char*)A_lo + off) = lv;
        }
        __syncthreads();   // drains A-writes + async B (+ any px loads in flight)

        // ---- prefetch x for ks+1: overlaps the MFMA block below ----
        if (ks < 31) {
#pragma unroll
            for (int r = 0; r < 2; ++r) {
                int u = r * 256 + t;
                int row = u >> 2, c8 = u & 3;
                const float4* xp = (const float4*)(x + (size_t)(m0 + row) * HD
                                                   + (ks + 1) * 32 + c8 * 8);
                px[r][0] = xp[0]; px[r][1] = xp[1];
            }
        }

        // ---- compute ----
        const short8* Bh = (const short8*)Bt;
        const short8* Bl = (const short8*)(Bt + 4096);
        short8 ah[4], al[4], bh[4], bl[4];
        const int xr = (l >> 4) << 5;
#pragma unroll
        for (int i = 0; i < 4; ++i) {
            int off = ((((wm * 4 + i) * 64 + l) * 16) ^ xr);
            ah[i] = *(const short8*)(Ahc + off);
            al[i] = *(const short8*)(Alc + off);
        }
#pragma unroll
        for (int j = 0; j < 4; ++j) {
            bh[j] = Bh[(wn * 4 + j) * 64 + l];
            bl[j] = Bl[(wn * 4 + j) * 64 + l];
        }
#pragma unroll
        for (int i = 0; i < 4; ++i)
#pragma unroll
            for (int j = 0; j < 4; ++j) {
                acc[i][j] = __builtin_amdgcn_mfma_f32_16x16x32_bf16(ah[i], bh[j], acc[i][j], 0, 0, 0);
                acc[i][j] = __builtin_amdgcn_mfma_f32_16x16x32_bf16(al[i], bh[j], acc[i][j], 0, 0, 0);
                acc[i][j] = __builtin_amdgcn_mfma_f32_16x16x32_bf16(ah[i], bl[j], acc[i][j], 0, 0, 0);
            }
    }

    // ---- epilogue: + bq, tanh, *vq, reduce over cols, atomicAdd ----
    // C/D layout: col = lane&15, row = (lane>>4)*4 + reg
    int q = l >> 4, c = l & 15;
#pragma unroll
    for (int i = 0; i < 4; ++i) {
        float rs[4] = {0.f, 0.f, 0.f, 0.f};
#pragma unroll
        for (int j = 0; j < 4; ++j) {
            int n = nb * 128 + wn * 64 + j * 16 + c;
            float bqv = bq[n], vqv = vq[n];
            f32x4 a4 = acc[i][j];
#pragma unroll
            for (int r = 0; r < 4; ++r)
                rs[r] += fast_tanh(a4[r] + bqv) * vqv;
        }
#pragma unroll
        for (int r = 0; r < 4; ++r) {
            float v = rs[r];
            v += __shfl_xor(v, 1);
            v += __shfl_xor(v, 2);
            v += __shfl_xor(v, 4);
            v += __shfl_xor(v, 8);
            if (c == 0)
                atomicAdd(&score[m0 + wm * 64 + i * 16 + q * 4 + r], v);
        }
    }
}

// -------- phase 2 (fused): masked softmax + weighted sum, one kernel -------
// grid (BS, 32): block (b, sc) recomputes softmax of row b (cheap, redundant
// x32) then accumulates rows [sc*16, sc*16+16) of x into out[b][:] via
// atomicAdd (out zero-memset in kernel_launch).
// KEY: masked rows have score = -1e6 -> exp underflows to exactly 0.0f, and
// ~half the rows are masked. The weight is uniform across the block, so
// `if (wv != 0)` is a wave-uniform branch that skips the whole 4 KB row
// load -> tail x-traffic ~268 MB -> ~134 MB. Also 4x more blocks (4096)
// with fully-unrolled 16-row loop in case the old tail was latency-bound.
__global__ void attend_kernel(const float* __restrict__ x,
                              const float* __restrict__ score,
                              const void* __restrict__ maskp,
                              const int* __restrict__ flag,
                              float* __restrict__ out) {
    __shared__ float red[8];
    __shared__ float wsh[SL];
    int b = blockIdx.x, sc = blockIdx.y, t = threadIdx.x;
    int w = t >> 6;
    bool u8 = (*flag != 0);
    int i0 = b * SL + t, i1 = i0 + 256;
    bool mk0, mk1;
    if (u8) {
        mk0 = ((const unsigned char*)maskp)[i0] != 0;
        mk1 = ((const unsigned char*)maskp)[i1] != 0;
    } else {
        mk0 = ((const int*)maskp)[i0] != 0;
        mk1 = ((const int*)maskp)[i1] != 0;
    }
    float s0 = mk0 ? -1000000.0f : score[i0];
    float s1 = mk1 ? -1000000.0f : score[i1];
    float mx = fmaxf(s0, s1);
    for (int d = 1; d < 64; d <<= 1) mx = fmaxf(mx, __shfl_xor(mx, d));
    if ((t & 63) == 0) red[w] = mx;
    __syncthreads();
    mx = fmaxf(fmaxf(red[0], red[1]), fmaxf(red[2], red[3]));
    float e0 = expf(s0 - mx), e1 = expf(s1 - mx);
    float sm = e0 + e1;
    for (int d = 1; d < 64; d <<= 1) sm += __shfl_xor(sm, d);
    if ((t & 63) == 0) red[4 + w] = sm;
    __syncthreads();
    sm = red[4] + red[5] + red[6] + red[7];
    float inv = 1.0f / sm;
    wsh[t] = e0 * inv;
    wsh[t + 256] = e1 * inv;
    __syncthreads();

    // weighted sum: 16 rows, each thread owns one float4 column of HD.
    // wv is block-uniform -> the !=0 branch is wave-uniform -> masked rows
    // (exactly-zero weight) skip their global loads entirely.
    const float* wp = wsh + sc * 16;
    const float4* xp = (const float4*)(x + ((size_t)b * SL + sc * 16) * HD) + t;
    float ax = 0.f, ay = 0.f, az = 0.f, aw = 0.f;
#pragma unroll
    for (int s = 0; s < 16; ++s) {
        float wv = wp[s];
        if (wv != 0.0f) {
            float4 v = xp[(size_t)s * 256];
            ax += wv * v.x; ay += wv * v.y; az += wv * v.z; aw += wv * v.w;
        }
    }
    float* op = out + (size_t)b * HD + t * 4;
    atomicAdd(op + 0, ax);
    atomicAdd(op + 1, ay);
    atomicAdd(op + 2, az);
    atomicAdd(op + 3, aw);
}

extern "C" void kernel_launch(void* const* d_in, const int* in_sizes, int n_in,
                              void* d_out, int out_size, void* d_ws, size_t ws_size,
                              hipStream_t stream) {
    const float* x  = (const float*)d_in[0];
    const void* mask = d_in[1];
    const float* Wq = (const float*)d_in[2];
    const float* bq = (const float*)d_in[3];
    const float* vq = (const float*)d_in[4];
    float* out = (float*)d_out;

    char* ws = (char*)d_ws;
    unsigned short* packW = (unsigned short*)ws;                       // 2 MB
    float* score   = (float*)(ws + (2u << 20));                        // 256 KB
    int*   flag    = (int*)  (ws + (2u << 20) + (256u << 10));         // 4 B

    hipMemsetAsync(score, 0, (256u << 10) + 4, stream);
    hipMemsetAsync(out, 0, (size_t)BS * HD * sizeof(float), stream);

    pack_wq_kernel<<<256, 256, 0, stream>>>(Wq, packW, (const unsigned*)mask, flag);
    score_kernel<<<2048, 256, 0, stream>>>(x, packW, bq, vq, score);
    attend_kernel<<<dim3(BS, 32), 256, 0, stream>>>(x, score, mask, flag, out);
}

// Round 4
// 522.298 us; speedup vs baseline: 1.0875x; 1.0875x over previous
//
#include <hip/hip_runtime.h>
#include <stdint.h>

#define BS 128
#define SL 512
#define HD 1024
#define DD 512
#define M_TOT (BS*SL)   // 65536

typedef __attribute__((ext_vector_type(8))) short short8;
typedef __attribute__((ext_vector_type(4))) float f32x4;

__device__ __forceinline__ unsigned short f32_bf16(float f) {
    union { float f; unsigned u; } v; v.f = f;
    unsigned u = v.u + 0x7FFFu + ((v.u >> 16) & 1u);
    return (unsigned short)(u >> 16);
}
__device__ __forceinline__ float bf16_f32(unsigned short h) {
    union { unsigned u; float f; } v; v.u = ((unsigned)h) << 16; return v.f;
}
__device__ __forceinline__ float u2f(unsigned u) {
    union { unsigned u; float f; } v; v.u = u; return v.f;
}
// packed 2xf32 -> 2xbf16 (RNE), one VOP3: d[15:0]=bf16(a), d[31:16]=bf16(b)
__device__ __forceinline__ unsigned cvt_pk_bf16(float a, float b) {
    unsigned r;
    asm("v_cvt_pk_bf16_f32 %0, %1, %2" : "=v"(r) : "v"(a), "v"(b));
    return r;
}
__device__ __forceinline__ float fast_tanh(float x) {
    float e = __expf(2.0f * x);
    return 1.0f - 2.0f / (e + 1.0f);
}
__device__ __forceinline__ void async_lds16(const void* g, void* l) {
    __builtin_amdgcn_global_load_lds(
        (const __attribute__((address_space(1))) unsigned int*)g,
        (__attribute__((address_space(3))) unsigned int*)l, 16, 0, 0);
}

// ---------------- pack Wq into bf16 hi/lo, MFMA-frag order (+ mask detect) --
__global__ void pack_wq_kernel(const float* __restrict__ Wq,
                               unsigned short* __restrict__ P,
                               const unsigned* __restrict__ mw,
                               int* __restrict__ flag) {
    if (blockIdx.x == 0) {
        unsigned bad = 0;
        for (int i = threadIdx.x; i < 1024; i += 256) bad |= (mw[i] > 1u) ? 1u : 0u;
        if (bad) atomicExch(flag, 1);
    }
    int t = blockIdx.x * 256 + threadIdx.x;   // 0..65535
    int d  = t >> 7;           // 0..511
    int h0 = (t & 127) << 3;   // 0..1016
    const float* src = Wq + (size_t)d * HD + h0;
    union { unsigned short s[8]; uint4 v; } a, b;
#pragma unroll
    for (int j = 0; j < 8; ++j) {
        float f = src[j];
        a.s[j] = f32_bf16(f);
        b.s[j] = f32_bf16(f - bf16_f32(a.s[j]));
    }
    int nb = d >> 7, cg = (d >> 4) & 7, lr = d & 15;
    int ks = h0 >> 5, q = (h0 >> 3) & 3;
    int l = q * 16 + lr;
    size_t base = (size_t)(nb * 32 + ks) * 8192 + (size_t)(cg * 64 + l) * 8;
    *(uint4*)(P + base)        = a.v;
    *(uint4*)(P + base + 4096) = b.v;
}

// ---------------- phase 1: score = vq . tanh(x @ Wq^T + bq) ----------------
// 128x128 tile, K=1024 in 32 steps. 4 waves (2x2), each 64x64 (4x4 of 16x16).
// 3-term bf16 split. UNCHANGED (217 us, MfmaUtil 42%, VGPR 64 = exactly the
// 128-reg/4-wave budget with 64 AGPR acc; 0 LDS bank conflicts).
// Pipe accounting: per CU 238K cyc MFMA (46% of total) vs measured 42% ->
// within ~8% of this instruction mix's issue requirement; LDS-read pipe
// (~768 cyc/block-ks of ds_read_b128) is co-balanced. Further gains need
// the 8-phase 256-tile schedule (deferred; high risk), not source tweaks.
__launch_bounds__(256, 4)
__global__ void score_kernel(const float* __restrict__ x,
                             const unsigned short* __restrict__ packW,
                             const float* __restrict__ bq,
                             const float* __restrict__ vq,
                             float* __restrict__ score) {
    __shared__ unsigned short A_hi[4096];   // 8 KB, frag order, XOR-swizzled
    __shared__ unsigned short A_lo[4096];   // 8 KB
    __shared__ unsigned short Bt[8192];     // 16 KB: hi[0..4095], lo[4096..]

    const int bid = blockIdx.x;
    const int xcd = bid & 7;
    const int slot = bid >> 3;              // 0..255
    const int nb = slot & 3;                // N tile of 128
    const int m0 = (xcd + ((slot >> 2) << 3)) << 7;  // row tile * 128

    const int t = threadIdx.x;
    const int l = t & 63;
    const int w = t >> 6;
    const int wm = w & 1, wn = w >> 1;      // 2x2 wave grid

    f32x4 acc[4][4];
#pragma unroll
    for (int i = 0; i < 4; ++i)
#pragma unroll
        for (int j = 0; j < 4; ++j)
            acc[i][j] = (f32x4){0.f, 0.f, 0.f, 0.f};

    const char* Ahc = (const char*)A_hi;
    const char* Alc = (const char*)A_lo;

    float4 px[2][2];
    // prefetch ks=0
#pragma unroll
    for (int r = 0; r < 2; ++r) {
        int u = r * 256 + t;
        int row = u >> 2, c8 = u & 3;
        const float4* xp = (const float4*)(x + (size_t)(m0 + row) * HD + c8 * 8);
        px[r][0] = xp[0]; px[r][1] = xp[1];
    }

    for (int ks = 0; ks < 32; ++ks) {
        __syncthreads();   // previous compute done -> LDS free
        // ---- stage B: async 16KB linear copy (frag-ordered in packW) ----
        {
            const unsigned short* src = packW + (size_t)(nb * 32 + ks) * 8192;
#pragma unroll
            for (int r = 0; r < 4; ++r)
                async_lds16(src + (size_t)(r * 256 + t) * 8, Bt + (r * 256 + t) * 8);
        }
        // ---- stage A: prefetched fp32 -> bf16 hi/lo via cvt_pk, swizzled ----
#pragma unroll
        for (int r = 0; r < 2; ++r) {
            int u = r * 256 + t;
            int row = u >> 2, c8 = u & 3;
            int rg = row >> 4, rr = row & 15;
            int off = (((rg * 64 + c8 * 16 + rr) * 16) ^ (c8 << 5));
            float4 v0 = px[r][0], v1 = px[r][1];
            unsigned h0 = cvt_pk_bf16(v0.x, v0.y);
            unsigned h1 = cvt_pk_bf16(v0.z, v0.w);
            unsigned h2 = cvt_pk_bf16(v1.x, v1.y);
            unsigned h3 = cvt_pk_bf16(v1.z, v1.w);
            unsigned l0 = cvt_pk_bf16(v0.x - u2f(h0 << 16), v0.y - u2f(h0 & 0xFFFF0000u));
            unsigned l1 = cvt_pk_bf16(v0.z - u2f(h1 << 16), v0.w - u2f(h1 & 0xFFFF0000u));
            unsigned l2 = cvt_pk_bf16(v1.x - u2f(h2 << 16), v1.y - u2f(h2 & 0xFFFF0000u));
            unsigned l3 = cvt_pk_bf16(v1.z - u2f(h3 << 16), v1.w - u2f(h3 & 0xFFFF0000u));
            uint4 hv = {h0, h1, h2, h3};
            uint4 lv = {l0, l1, l2, l3};
            *(uint4*)((char*)A_hi + off) = hv;
            *(uint4*)((char*)A_lo + off) = lv;
        }
        __syncthreads();   // drains A-writes + async B (+ any px loads in flight)

        // ---- prefetch x for ks+1: overlaps the MFMA block below ----
        if (ks < 31) {
#pragma unroll
            for (int r = 0; r < 2; ++r) {
                int u = r * 256 + t;
                int row = u >> 2, c8 = u & 3;
                const float4* xp = (const float4*)(x + (size_t)(m0 + row) * HD
                                                   + (ks + 1) * 32 + c8 * 8);
                px[r][0] = xp[0]; px[r][1] = xp[1];
            }
        }

        // ---- compute ----
        const short8* Bh = (const short8*)Bt;
        const short8* Bl = (const short8*)(Bt + 4096);
        short8 ah[4], al[4], bh[4], bl[4];
        const int xr = (l >> 4) << 5;
#pragma unroll
        for (int i = 0; i < 4; ++i) {
            int off = ((((wm * 4 + i) * 64 + l) * 16) ^ xr);
            ah[i] = *(const short8*)(Ahc + off);
            al[i] = *(const short8*)(Alc + off);
        }
#pragma unroll
        for (int j = 0; j < 4; ++j) {
            bh[j] = Bh[(wn * 4 + j) * 64 + l];
            bl[j] = Bl[(wn * 4 + j) * 64 + l];
        }
#pragma unroll
        for (int i = 0; i < 4; ++i)
#pragma unroll
            for (int j = 0; j < 4; ++j) {
                acc[i][j] = __builtin_amdgcn_mfma_f32_16x16x32_bf16(ah[i], bh[j], acc[i][j], 0, 0, 0);
                acc[i][j] = __builtin_amdgcn_mfma_f32_16x16x32_bf16(al[i], bh[j], acc[i][j], 0, 0, 0);
                acc[i][j] = __builtin_amdgcn_mfma_f32_16x16x32_bf16(ah[i], bl[j], acc[i][j], 0, 0, 0);
            }
    }

    // ---- epilogue: + bq, tanh, *vq, reduce over cols, atomicAdd ----
    // C/D layout: col = lane&15, row = (lane>>4)*4 + reg
    int q = l >> 4, c = l & 15;
#pragma unroll
    for (int i = 0; i < 4; ++i) {
        float rs[4] = {0.f, 0.f, 0.f, 0.f};
#pragma unroll
        for (int j = 0; j < 4; ++j) {
            int n = nb * 128 + wn * 64 + j * 16 + c;
            float bqv = bq[n], vqv = vq[n];
            f32x4 a4 = acc[i][j];
#pragma unroll
            for (int r = 0; r < 4; ++r)
                rs[r] += fast_tanh(a4[r] + bqv) * vqv;
        }
#pragma unroll
        for (int r = 0; r < 4; ++r) {
            float v = rs[r];
            v += __shfl_xor(v, 1);
            v += __shfl_xor(v, 2);
            v += __shfl_xor(v, 4);
            v += __shfl_xor(v, 8);
            if (c == 0)
                atomicAdd(&score[m0 + wm * 64 + i * 16 + q * 4 + r], v);
        }
    }
}

// -------- phase 2 (fused): masked softmax + weighted sum, one kernel -------
// grid (BS, 8): block (b, sc) recomputes softmax of row b (cheap, redundant
// x8), COMPACTS the indices of nonzero-weight rows in its 64-row strip
// (masked rows' weights underflow to exactly 0.0f; ~half are masked), then
// runs a DENSE unguarded loop over the ~32 survivors. Dense loop keeps 4+
// independent loads in flight (R3's per-row guard killed MLP), halves
// x-traffic, and keeps atomics at R2's 1M/8-way level.
// All-masked edge case: weights become uniform 1/512 != 0 -> nothing skipped.
__global__ void attend_kernel(const float* __restrict__ x,
                              const float* __restrict__ score,
                              const void* __restrict__ maskp,
                              const int* __restrict__ flag,
                              float* __restrict__ out) {
    __shared__ float red[8];
    __shared__ float wsh[SL];
    __shared__ int   lst[64];
    __shared__ float wlst[64];
    __shared__ int   cntS;
    int b = blockIdx.x, sc = blockIdx.y, t = threadIdx.x;
    int w = t >> 6;
    bool u8 = (*flag != 0);
    int i0 = b * SL + t, i1 = i0 + 256;
    bool mk0, mk1;
    if (u8) {
        mk0 = ((const unsigned char*)maskp)[i0] != 0;
        mk1 = ((const unsigned char*)maskp)[i1] != 0;
    } else {
        mk0 = ((const int*)maskp)[i0] != 0;
        mk1 = ((const int*)maskp)[i1] != 0;
    }
    float s0 = mk0 ? -1000000.0f : score[i0];
    float s1 = mk1 ? -1000000.0f : score[i1];
    float mx = fmaxf(s0, s1);
    for (int d = 1; d < 64; d <<= 1) mx = fmaxf(mx, __shfl_xor(mx, d));
    if ((t & 63) == 0) red[w] = mx;
    __syncthreads();
    mx = fmaxf(fmaxf(red[0], red[1]), fmaxf(red[2], red[3]));
    float e0 = expf(s0 - mx), e1 = expf(s1 - mx);
    float sm = e0 + e1;
    for (int d = 1; d < 64; d <<= 1) sm += __shfl_xor(sm, d);
    if ((t & 63) == 0) red[4 + w] = sm;
    __syncthreads();
    sm = red[4] + red[5] + red[6] + red[7];
    float inv = 1.0f / sm;
    wsh[t] = e0 * inv;
    wsh[t + 256] = e1 * inv;
    __syncthreads();

    // ---- compact nonzero-weight rows of this block's 64-row strip ----
    if (t < 64) {
        float wv = wsh[sc * 64 + t];
        bool nz = (wv != 0.0f);
        unsigned long long m = __ballot(nz);
        int pos = __popcll(m & ((1ULL << t) - 1ULL));
        if (nz) { lst[pos] = t; wlst[pos] = wv; }
        if (t == 0) cntS = (int)__popcll(m);
    }
    __syncthreads();
    int cnt = cntS;

    // ---- dense weighted sum over surviving rows ----
    const float4* xb = (const float4*)(x + ((size_t)b * SL + sc * 64) * HD) + t;
    float ax = 0.f, ay = 0.f, az = 0.f, aw = 0.f;
#pragma unroll 4
    for (int s = 0; s < cnt; ++s) {
        int row = lst[s];
        float wv = wlst[s];
        float4 v = xb[(size_t)row * 256];
        ax += wv * v.x; ay += wv * v.y; az += wv * v.z; aw += wv * v.w;
    }
    float* op = out + (size_t)b * HD + t * 4;
    atomicAdd(op + 0, ax);
    atomicAdd(op + 1, ay);
    atomicAdd(op + 2, az);
    atomicAdd(op + 3, aw);
}

extern "C" void kernel_launch(void* const* d_in, const int* in_sizes, int n_in,
                              void* d_out, int out_size, void* d_ws, size_t ws_size,
                              hipStream_t stream) {
    const float* x  = (const float*)d_in[0];
    const void* mask = d_in[1];
    const float* Wq = (const float*)d_in[2];
    const float* bq = (const float*)d_in[3];
    const float* vq = (const float*)d_in[4];
    float* out = (float*)d_out;

    char* ws = (char*)d_ws;
    unsigned short* packW = (unsigned short*)ws;                       // 2 MB
    float* score   = (float*)(ws + (2u << 20));                        // 256 KB
    int*   flag    = (int*)  (ws + (2u << 20) + (256u << 10));         // 4 B

    hipMemsetAsync(score, 0, (256u << 10) + 4, stream);
    hipMemsetAsync(out, 0, (size_t)BS * HD * sizeof(float), stream);

    pack_wq_kernel<<<256, 256, 0, stream>>>(Wq, packW, (const unsigned*)mask, flag);
    score_kernel<<<2048, 256, 0, stream>>>(x, packW, bq, vq, score);
    attend_kernel<<<dim3(BS, 8), 256, 0, stream>>>(x, score, mask, flag, out);
}

// Round 5
// 507.581 us; speedup vs baseline: 1.1190x; 1.0290x over previous
//
#include <hip/hip_runtime.h>
#include <stdint.h>

#define BS 128
#define SL 512
#define HD 1024
#define DD 512
#define M_TOT (BS*SL)   // 65536

typedef __attribute__((ext_vector_type(8))) short short8;
typedef __attribute__((ext_vector_type(4))) float f32x4;

__device__ __forceinline__ unsigned short f32_bf16(float f) {
    union { float f; unsigned u; } v; v.f = f;
    unsigned u = v.u + 0x7FFFu + ((v.u >> 16) & 1u);
    return (unsigned short)(u >> 16);
}
__device__ __forceinline__ float bf16_f32(unsigned short h) {
    union { unsigned u; float f; } v; v.u = ((unsigned)h) << 16; return v.f;
}
__device__ __forceinline__ float u2f(unsigned u) {
    union { unsigned u; float f; } v; v.u = u; return v.f;
}
// packed 2xf32 -> 2xbf16 (RNE), one VOP3: d[15:0]=bf16(a), d[31:16]=bf16(b)
__device__ __forceinline__ unsigned cvt_pk_bf16(float a, float b) {
    unsigned r;
    asm("v_cvt_pk_bf16_f32 %0, %1, %2" : "=v"(r) : "v"(a), "v"(b));
    return r;
}
__device__ __forceinline__ float fast_tanh(float x) {
    float e = __expf(2.0f * x);
    return 1.0f - 2.0f / (e + 1.0f);
}
__device__ __forceinline__ void async_lds16(const void* g, void* l) {
    __builtin_amdgcn_global_load_lds(
        (const __attribute__((address_space(1))) unsigned int*)g,
        (__attribute__((address_space(3))) unsigned int*)l, 16, 0, 0);
}

// ---------------- pack Wq into bf16 hi/lo, MFMA-frag order (+ mask detect) --
__global__ void pack_wq_kernel(const float* __restrict__ Wq,
                               unsigned short* __restrict__ P,
                               const unsigned* __restrict__ mw,
                               int* __restrict__ flag) {
    if (blockIdx.x == 0) {
        unsigned bad = 0;
        for (int i = threadIdx.x; i < 1024; i += 256) bad |= (mw[i] > 1u) ? 1u : 0u;
        if (bad) atomicExch(flag, 1);
    }
    int t = blockIdx.x * 256 + threadIdx.x;   // 0..65535
    int d  = t >> 7;           // 0..511
    int h0 = (t & 127) << 3;   // 0..1016
    const float* src = Wq + (size_t)d * HD + h0;
    union { unsigned short s[8]; uint4 v; } a, b;
#pragma unroll
    for (int j = 0; j < 8; ++j) {
        float f = src[j];
        a.s[j] = f32_bf16(f);
        b.s[j] = f32_bf16(f - bf16_f32(a.s[j]));
    }
    int nb = d >> 7, cg = (d >> 4) & 7, lr = d & 15;
    int ks = h0 >> 5, q = (h0 >> 3) & 3;
    int l = q * 16 + lr;
    size_t base = (size_t)(nb * 32 + ks) * 8192 + (size_t)(cg * 64 + l) * 8;
    *(uint4*)(P + base)        = a.v;
    *(uint4*)(P + base + 4096) = b.v;
}

// ---------------- phase 1: score = vq . tanh(x @ Wq^T + bq) ----------------
// 128x128 tile, K=1024 in 32 steps. 4 waves (2x2), each 64x64 (4x4 of 16x16).
// 3-term bf16 split. COUNTED-PIPELINE restructure (this round): B tile is
// double-buffered in LDS; A stays single-buffered. Per step, issue order is
// pinned with sched_barrier(0): [4x gll B(ks+1) -> Bt[cur^1]] -> [convert px
// -> A writes] -> [4x px loads x(ks+1)]. vmem retires IN ORDER, so the
// compiler-inserted wait when px is consumed next step implicitly retires
// the previous step's B-glls; barrier2 needs only lgkmcnt(0). NO vmcnt(0)
// drain anywhere in the loop -- B-glls/px stay in flight across barriers
// for a full step (packW is L2-resident; latency hidden).
// LDS 48 KB -> 3 blocks/CU (LDS-capped; small VGPR inflation is free).
__launch_bounds__(256, 3)
__global__ void score_kernel(const float* __restrict__ x,
                             const unsigned short* __restrict__ packW,
                             const float* __restrict__ bq,
                             const float* __restrict__ vq,
                             float* __restrict__ score) {
    __shared__ unsigned short A_hi[4096];     // 8 KB, frag order, XOR-swizzled
    __shared__ unsigned short A_lo[4096];     // 8 KB
    __shared__ unsigned short Bt[2][8192];    // 2 x 16 KB: hi[0..4095], lo[4096..]

    const int bid = blockIdx.x;
    const int xcd = bid & 7;
    const int slot = bid >> 3;              // 0..255
    const int nb = slot & 3;                // N tile of 128
    const int m0 = (xcd + ((slot >> 2) << 3)) << 7;  // row tile * 128

    const int t = threadIdx.x;
    const int l = t & 63;
    const int w = t >> 6;
    const int wm = w & 1, wn = w >> 1;      // 2x2 wave grid

    f32x4 acc[4][4];
#pragma unroll
    for (int i = 0; i < 4; ++i)
#pragma unroll
        for (int j = 0; j < 4; ++j)
            acc[i][j] = (f32x4){0.f, 0.f, 0.f, 0.f};

    const char* Ahc = (const char*)A_hi;
    const char* Alc = (const char*)A_lo;

    float4 px[2][2];
    // ---- prologue: issue B(0) glls FIRST (so px is newer), then px <- x(0)
    {
        const unsigned short* src = packW + (size_t)(nb * 32) * 8192;
#pragma unroll
        for (int r = 0; r < 4; ++r)
            async_lds16(src + (size_t)(r * 256 + t) * 8,
                        (unsigned short*)Bt[0] + (r * 256 + t) * 8);
    }
    __builtin_amdgcn_sched_barrier(0);
#pragma unroll
    for (int r = 0; r < 2; ++r) {
        int u = r * 256 + t;
        int row = u >> 2, c8 = u & 3;
        const float4* xp = (const float4*)(x + (size_t)(m0 + row) * HD + c8 * 8);
        px[r][0] = xp[0]; px[r][1] = xp[1];
    }

    for (int ks = 0; ks < 32; ++ks) {
        const int cur = ks & 1;
        // ---- stage B(ks+1) into the other buffer (oldest vmem this step) --
        if (ks < 31) {
            const unsigned short* src = packW + (size_t)(nb * 32 + ks + 1) * 8192;
#pragma unroll
            for (int r = 0; r < 4; ++r)
                async_lds16(src + (size_t)(r * 256 + t) * 8,
                            (unsigned short*)Bt[cur ^ 1] + (r * 256 + t) * 8);
        }
        __builtin_amdgcn_sched_barrier(0);   // pin: glls strictly before px
        // ---- convert px (x for THIS step) -> A_hi/A_lo (consuming px
        //      retires all older vmem = last step's B-glls, in-order) -------
#pragma unroll
        for (int r = 0; r < 2; ++r) {
            int u = r * 256 + t;
            int row = u >> 2, c8 = u & 3;
            int rg = row >> 4, rr = row & 15;
            int off = (((rg * 64 + c8 * 16 + rr) * 16) ^ (c8 << 5));
            float4 v0 = px[r][0], v1 = px[r][1];
            unsigned h0 = cvt_pk_bf16(v0.x, v0.y);
            unsigned h1 = cvt_pk_bf16(v0.z, v0.w);
            unsigned h2 = cvt_pk_bf16(v1.x, v1.y);
            unsigned h3 = cvt_pk_bf16(v1.z, v1.w);
            unsigned l0 = cvt_pk_bf16(v0.x - u2f(h0 << 16), v0.y - u2f(h0 & 0xFFFF0000u));
            unsigned l1 = cvt_pk_bf16(v0.z - u2f(h1 << 16), v0.w - u2f(h1 & 0xFFFF0000u));
            unsigned l2 = cvt_pk_bf16(v1.x - u2f(h2 << 16), v1.y - u2f(h2 & 0xFFFF0000u));
            unsigned l3 = cvt_pk_bf16(v1.z - u2f(h3 << 16), v1.w - u2f(h3 & 0xFFFF0000u));
            uint4 hv = {h0, h1, h2, h3};
            uint4 lv = {l0, l1, l2, l3};
            *(uint4*)((char*)A_hi + off) = hv;
            *(uint4*)((char*)A_lo + off) = lv;
        }
        // ---- prefetch x for step ks+1 (newest vmem this step) -------------
        if (ks < 31) {
#pragma unroll
            for (int r = 0; r < 2; ++r) {
                int u = r * 256 + t;
                int row = u >> 2, c8 = u & 3;
                const float4* xp = (const float4*)(x + (size_t)(m0 + row) * HD
                                                   + (ks + 1) * 32 + c8 * 8);
                px[r][0] = xp[0]; px[r][1] = xp[1];
            }
        }
        __builtin_amdgcn_sched_barrier(0);   // keep px issue inside this region
        asm volatile("s_waitcnt lgkmcnt(0)" ::: "memory");  // A-writes visible
        __builtin_amdgcn_s_barrier();        // barrier2: NO vmcnt drain

        // ---- compute from A and Bt[cur] ----
        const short8* Bh = (const short8*)Bt[cur];
        const short8* Bl = (const short8*)(Bt[cur] + 4096);
        short8 ah[4], al[4], bh[4], bl[4];
        const int xr = (l >> 4) << 5;
#pragma unroll
        for (int i = 0; i < 4; ++i) {
            int off = ((((wm * 4 + i) * 64 + l) * 16) ^ xr);
            ah[i] = *(const short8*)(Ahc + off);
            al[i] = *(const short8*)(Alc + off);
        }
#pragma unroll
        for (int j = 0; j < 4; ++j) {
            bh[j] = Bh[(wn * 4 + j) * 64 + l];
            bl[j] = Bl[(wn * 4 + j) * 64 + l];
        }
#pragma unroll
        for (int i = 0; i < 4; ++i)
#pragma unroll
            for (int j = 0; j < 4; ++j) {
                acc[i][j] = __builtin_amdgcn_mfma_f32_16x16x32_bf16(ah[i], bh[j], acc[i][j], 0, 0, 0);
                acc[i][j] = __builtin_amdgcn_mfma_f32_16x16x32_bf16(al[i], bh[j], acc[i][j], 0, 0, 0);
                acc[i][j] = __builtin_amdgcn_mfma_f32_16x16x32_bf16(ah[i], bl[j], acc[i][j], 0, 0, 0);
            }

        // barrier1: next step overwrites A (single-buf) and Bt[cur^...] -----
        __builtin_amdgcn_s_barrier();
    }

    // ---- epilogue: + bq, tanh, *vq, reduce over cols, atomicAdd ----
    // C/D layout: col = lane&15, row = (lane>>4)*4 + reg
    int q = l >> 4, c = l & 15;
#pragma unroll
    for (int i = 0; i < 4; ++i) {
        float rs[4] = {0.f, 0.f, 0.f, 0.f};
#pragma unroll
        for (int j = 0; j < 4; ++j) {
            int n = nb * 128 + wn * 64 + j * 16 + c;
            float bqv = bq[n], vqv = vq[n];
            f32x4 a4 = acc[i][j];
#pragma unroll
            for (int r = 0; r < 4; ++r)
                rs[r] += fast_tanh(a4[r] + bqv) * vqv;
        }
#pragma unroll
        for (int r = 0; r < 4; ++r) {
            float v = rs[r];
            v += __shfl_xor(v, 1);
            v += __shfl_xor(v, 2);
            v += __shfl_xor(v, 4);
            v += __shfl_xor(v, 8);
            if (c == 0)
                atomicAdd(&score[m0 + wm * 64 + i * 16 + q * 4 + r], v);
        }
    }
}

// -------- phase 2 (fused): masked softmax + weighted sum, one kernel -------
// grid (BS, 8): block (b, sc) recomputes softmax of row b (cheap, redundant
// x8), COMPACTS the indices of nonzero-weight rows in its 64-row strip
// (masked rows' weights underflow to exactly 0.0f; ~half are masked), then
// runs a DENSE unguarded loop over the ~32 survivors. Tail is at its floor
// (~305 us total residual is ~250 us fixed harness overhead + ~55 us work,
// invariant across 5 structural variants R0-R4).
__global__ void attend_kernel(const float* __restrict__ x,
                              const float* __restrict__ score,
                              const void* __restrict__ maskp,
                              const int* __restrict__ flag,
                              float* __restrict__ out) {
    __shared__ float red[8];
    __shared__ float wsh[SL];
    __shared__ int   lst[64];
    __shared__ float wlst[64];
    __shared__ int   cntS;
    int b = blockIdx.x, sc = blockIdx.y, t = threadIdx.x;
    int w = t >> 6;
    bool u8 = (*flag != 0);
    int i0 = b * SL + t, i1 = i0 + 256;
    bool mk0, mk1;
    if (u8) {
        mk0 = ((const unsigned char*)maskp)[i0] != 0;
        mk1 = ((const unsigned char*)maskp)[i1] != 0;
    } else {
        mk0 = ((const int*)maskp)[i0] != 0;
        mk1 = ((const int*)maskp)[i1] != 0;
    }
    float s0 = mk0 ? -1000000.0f : score[i0];
    float s1 = mk1 ? -1000000.0f : score[i1];
    float mx = fmaxf(s0, s1);
    for (int d = 1; d < 64; d <<= 1) mx = fmaxf(mx, __shfl_xor(mx, d));
    if ((t & 63) == 0) red[w] = mx;
    __syncthreads();
    mx = fmaxf(fmaxf(red[0], red[1]), fmaxf(red[2], red[3]));
    float e0 = expf(s0 - mx), e1 = expf(s1 - mx);
    float sm = e0 + e1;
    for (int d = 1; d < 64; d <<= 1) sm += __shfl_xor(sm, d);
    if ((t & 63) == 0) red[4 + w] = sm;
    __syncthreads();
    sm = red[4] + red[5] + red[6] + red[7];
    float inv = 1.0f / sm;
    wsh[t] = e0 * inv;
    wsh[t + 256] = e1 * inv;
    __syncthreads();

    // ---- compact nonzero-weight rows of this block's 64-row strip ----
    if (t < 64) {
        float wv = wsh[sc * 64 + t];
        bool nz = (wv != 0.0f);
        unsigned long long m = __ballot(nz);
        int pos = __popcll(m & ((1ULL << t) - 1ULL));
        if (nz) { lst[pos] = t; wlst[pos] = wv; }
        if (t == 0) cntS = (int)__popcll(m);
    }
    __syncthreads();
    int cnt = cntS;

    // ---- dense weighted sum over surviving rows ----
    const float4* xb = (const float4*)(x + ((size_t)b * SL + sc * 64) * HD) + t;
    float ax = 0.f, ay = 0.f, az = 0.f, aw = 0.f;
#pragma unroll 4
    for (int s = 0; s < cnt; ++s) {
        int row = lst[s];
        float wv = wlst[s];
        float4 v = xb[(size_t)row * 256];
        ax += wv * v.x; ay += wv * v.y; az += wv * v.z; aw += wv * v.w;
    }
    float* op = out + (size_t)b * HD + t * 4;
    atomicAdd(op + 0, ax);
    atomicAdd(op + 1, ay);
    atomicAdd(op + 2, az);
    atomicAdd(op + 3, aw);
}

extern "C" void kernel_launch(void* const* d_in, const int* in_sizes, int n_in,
                              void* d_out, int out_size, void* d_ws, size_t ws_size,
                              hipStream_t stream) {
    const float* x  = (const float*)d_in[0];
    const void* mask = d_in[1];
    const float* Wq = (const float*)d_in[2];
    const float* bq = (const float*)d_in[3];
    const float* vq = (const float*)d_in[4];
    float* out = (float*)d_out;

    char* ws = (char*)d_ws;
    unsigned short* packW = (unsigned short*)ws;                       // 2 MB
    float* score   = (float*)(ws + (2u << 20));                        // 256 KB
    int*   flag    = (int*)  (ws + (2u << 20) + (256u << 10));         // 4 B

    hipMemsetAsync(score, 0, (256u << 10) + 4, stream);
    hipMemsetAsync(out, 0, (size_t)BS * HD * sizeof(float), stream);

    pack_wq_kernel<<<256, 256, 0, stream>>>(Wq, packW, (const unsigned*)mask, flag);
    score_kernel<<<2048, 256, 0, stream>>>(x, packW, bq, vq, score);
    attend_kernel<<<dim3(BS, 8), 256, 0, stream>>>(x, score, mask, flag, out);
}